// Round 6
// baseline (63.971 us; speedup 1.0000x reference)
//
#include <hip/hip_runtime.h>
#include <hip/hip_bf16.h>

typedef __attribute__((ext_vector_type(8))) short short8;
typedef __attribute__((ext_vector_type(4))) float f32x4;

// bf16 truncation (round-toward-zero). Safe: s = ||z3||^2 cancels exactly in
// out = s*d / max(s*sqrt(n1*n2), eps); only d,n1,n2 (pure f32) reach out.
__device__ __forceinline__ unsigned int bfhi(float f) {
    return __builtin_bit_cast(unsigned int, f);
}
__device__ __forceinline__ unsigned int pack2(float lo, float hi) {
    return (bfhi(lo) >> 16) | (bfhi(hi) & 0xffff0000u);
}
__device__ __forceinline__ short8 pack_bf8(float4 a, float4 b) {
    uint4 u;
    u.x = pack2(a.x, a.y);
    u.y = pack2(a.z, a.w);
    u.z = pack2(b.x, b.y);
    u.w = pack2(b.z, b.w);
    return __builtin_bit_cast(short8, u);
}

// Single heterogeneous kernel, 576 blocks x 512 threads, <=128 VGPR, ~61KB LDS
// -> 2 blocks/CU.
//   bid 0..63   (Q): 64 rows each. 3 K-tiles: stage Xq f32->bf16 LDS, GEMM1
//                    (wave w owns 16 W1 cols x 4 M-subtiles); GEMM2/3 with
//                    in-register W2/W3 packing; s=||z3||^2 in LDS; then
//                    acquire-spin for its 8 P-blocks and write final out.
//   bid 64..575 (P): 8 rows each (wave w = row w): stream Xp1/Xp2, butterfly-
//                    reduce d,n1,n2 -> wsf, release-publish pflag. Blocks
//                    64..71 first convert W1 -> bf16 (wsb), publish wflag.
// d_ws layout: wsf d@0, n1@4096, n2@8192 (f32); wsb (ushort) @ float idx 12288;
// flags (int) @ byte 266240: wflag@[0], pflag[64]@[1..64].
__global__ __launch_bounds__(512, 4) void fused_pq(
    const float* __restrict__ X,
    const float* __restrict__ W1, const float* __restrict__ b1,
    const float* __restrict__ W2, const float* __restrict__ b2,
    const float* __restrict__ W3, const float* __restrict__ b3,
    float* __restrict__ wsf, unsigned short* __restrict__ wsb,
    int* __restrict__ flags, float* __restrict__ out)
{
    __shared__ __align__(16) unsigned short xq[64][264];  // 64x256 bf16 K-tile
    __shared__ __align__(16) unsigned short z1[64][136];  // 64x128 bf16
    __shared__ __align__(16) unsigned short z2[64][72];   // 64x64  bf16
    __shared__ float sred[2][64];

    const int tid  = threadIdx.x;
    const int wid  = tid >> 6;
    const int lane = tid & 63;
    const int l15  = lane & 15;
    const int l4   = lane >> 4;
    const int bid  = blockIdx.x;

    if (bid >= 64) {
        // ================= P path =================
        const int pb = bid - 64;                 // 0..511
        if (pb < 8) {
            // convert W1 slice (98304/8 = 12288 elems) -> bf16 in wsb
            for (int i = pb * 12288 + tid; i < (pb + 1) * 12288; i += 512)
                wsb[i] = (unsigned short)(bfhi(W1[i]) >> 16);
            __syncthreads();
            if (tid == 0) {
                __threadfence();
                __hip_atomic_fetch_add(&flags[0], 1, __ATOMIC_RELEASE, __HIP_MEMORY_SCOPE_AGENT);
            }
        }
        const int row = pb * 8 + wid;
        const float* base = X + (size_t)row * 2304;
        float4 p1[3], p2[3];
#pragma unroll
        for (int m = 0; m < 3; ++m) p1[m] = *(const float4*)(base + 768 + (lane + 64 * m) * 4);
#pragma unroll
        for (int m = 0; m < 3; ++m) p2[m] = *(const float4*)(base + 1536 + (lane + 64 * m) * 4);
        float dd = 0.f, aa = 0.f, bb = 0.f;
#pragma unroll
        for (int m = 0; m < 3; ++m) {
            float4 x = p1[m], y = p2[m];
            dd += x.x * y.x + x.y * y.y + x.z * y.z + x.w * y.w;
            aa += x.x * x.x + x.y * x.y + x.z * x.z + x.w * x.w;
            bb += y.x * y.x + y.y * y.y + y.z * y.z + y.w * y.w;
        }
#pragma unroll
        for (int m = 1; m < 64; m <<= 1) {
            dd += __shfl_xor(dd, m);
            aa += __shfl_xor(aa, m);
            bb += __shfl_xor(bb, m);
        }
        if (lane == 0) {
            wsf[row]        = dd;
            wsf[4096 + row] = aa;
            wsf[8192 + row] = bb;
        }
        __syncthreads();
        if (tid == 0) {
            __threadfence();
            __hip_atomic_fetch_add(&flags[1 + (pb >> 3)], 1, __ATOMIC_RELEASE, __HIP_MEMORY_SCOPE_AGENT);
        }
        return;
    }

    // ================= Q path (bid 0..63) =================
    const int g    = bid;
    const int row0 = g * 64;

    // ---- GEMM1: z1 = relu(Xq @ W1^T + b1), M=64, N=128, K=768 ----
    f32x4 acc[4] = {{0,0,0,0},{0,0,0,0},{0,0,0,0},{0,0,0,0}};
    const unsigned short* bp = wsb + (size_t)(16 * wid + l15) * 768 + l4 * 8;
    for (int kt = 0; kt < 3; ++kt) {
        // stage 64 rows x 256 cols f32 -> bf16 LDS
#pragma unroll
        for (int m = 0; m < 8; ++m) {
            int i = tid + 512 * m;           // 0..4095
            int r = i >> 6, c4 = i & 63;     // row, float4-slot in tile
            float4 v = *(const float4*)(X + (size_t)(row0 + r) * 2304 + kt * 256 + c4 * 4);
            uint2 qb;
            qb.x = pack2(v.x, v.y);
            qb.y = pack2(v.z, v.w);
            *(uint2*)&xq[r][c4 * 4] = qb;
        }
        if (kt == 0) {
            // W1 bf16 conversion (P-blocks 64..71) overlaps the stage above;
            // by here it is essentially always done.
            if (tid == 0) {
                while (__hip_atomic_load(&flags[0], __ATOMIC_ACQUIRE, __HIP_MEMORY_SCOPE_AGENT) < 8)
                    __builtin_amdgcn_s_sleep(1);
            }
        }
        __syncthreads();
#pragma unroll
        for (int k0 = 0; k0 < 256; k0 += 32) {
            short8 b = *(const short8*)(bp + kt * 256 + k0);
#pragma unroll
            for (int m = 0; m < 4; ++m) {
                short8 a = *(const short8*)&xq[16 * m + l15][k0 + l4 * 8];
                acc[m] = __builtin_amdgcn_mfma_f32_16x16x32_bf16(a, b, acc[m], 0, 0, 0);
            }
        }
        __syncthreads();  // before next stage overwrites xq
    }
    {
        float bv = b1[16 * wid + l15];
#pragma unroll
        for (int m = 0; m < 4; ++m)
#pragma unroll
            for (int r = 0; r < 4; ++r) {
                float v = fmaxf(acc[m][r] + bv, 0.f);
                z1[16 * m + 4 * l4 + r][16 * wid + l15] = (unsigned short)(bfhi(v) >> 16);
            }
    }
    __syncthreads();

    // ---- GEMM2: z2 = relu(z1 @ W2^T + b2), M=64, N=64, K=128 (W2 f32, packed in-reg) ----
    {
        const int ms = wid & 3, nh = wid >> 2;
        f32x4 a2[2] = {{0,0,0,0},{0,0,0,0}};
        const float* w2p0 = W2 + (size_t)(32 * nh + l15) * 128 + l4 * 8;
        const float* w2p1 = W2 + (size_t)(32 * nh + 16 + l15) * 128 + l4 * 8;
#pragma unroll
        for (int k0 = 0; k0 < 128; k0 += 32) {
            short8 a = *(const short8*)&z1[16 * ms + l15][k0 + l4 * 8];
            short8 w0 = pack_bf8(*(const float4*)(w2p0 + k0), *(const float4*)(w2p0 + k0 + 4));
            short8 w1 = pack_bf8(*(const float4*)(w2p1 + k0), *(const float4*)(w2p1 + k0 + 4));
            a2[0] = __builtin_amdgcn_mfma_f32_16x16x32_bf16(a, w0, a2[0], 0, 0, 0);
            a2[1] = __builtin_amdgcn_mfma_f32_16x16x32_bf16(a, w1, a2[1], 0, 0, 0);
        }
        float bv0 = b2[32 * nh + l15], bv1 = b2[32 * nh + 16 + l15];
#pragma unroll
        for (int r = 0; r < 4; ++r) {
            float v0 = fmaxf(a2[0][r] + bv0, 0.f);
            float v1 = fmaxf(a2[1][r] + bv1, 0.f);
            z2[16 * ms + 4 * l4 + r][32 * nh + l15]      = (unsigned short)(bfhi(v0) >> 16);
            z2[16 * ms + 4 * l4 + r][32 * nh + 16 + l15] = (unsigned short)(bfhi(v1) >> 16);
        }
    }
    __syncthreads();

    // ---- GEMM3: z3 = relu(z2 @ W3^T + b3), M=64, N=32, K=64; s = ||z3||^2 ----
    {
        const int ms = wid & 3, gg = wid >> 2;   // gg in {0,1}
        f32x4 a3 = {0, 0, 0, 0};
        const float* w3p = W3 + (size_t)(16 * gg + l15) * 64 + l4 * 8;
#pragma unroll
        for (int k0 = 0; k0 < 64; k0 += 32) {
            short8 a = *(const short8*)&z2[16 * ms + l15][k0 + l4 * 8];
            short8 b = pack_bf8(*(const float4*)(w3p + k0), *(const float4*)(w3p + k0 + 4));
            a3 = __builtin_amdgcn_mfma_f32_16x16x32_bf16(a, b, a3, 0, 0, 0);
        }
        float bv = b3[16 * gg + l15];
        float sv[4];
#pragma unroll
        for (int r = 0; r < 4; ++r) {
            float v = fmaxf(a3[r] + bv, 0.f);
            sv[r] = v * v;
        }
#pragma unroll
        for (int m = 1; m < 16; m <<= 1)
#pragma unroll
            for (int r = 0; r < 4; ++r) sv[r] += __shfl_xor(sv[r], m);
        if (l15 == 0)
#pragma unroll
            for (int r = 0; r < 4; ++r) sred[gg][16 * ms + 4 * l4 + r] = sv[r];
    }
    __syncthreads();

    // ---- wait for this group's 8 P-blocks, then combine ----
    if (tid == 0) {
        while (__hip_atomic_load(&flags[1 + g], __ATOMIC_ACQUIRE, __HIP_MEMORY_SCOPE_AGENT) < 8)
            __builtin_amdgcn_s_sleep(1);
    }
    __syncthreads();
    if (tid < 64) {
        int row  = row0 + tid;
        float s  = sred[0][tid] + sred[1][tid];
        float d  = wsf[row];
        float n1 = wsf[4096 + row];
        float n2 = wsf[8192 + row];
        out[row] = (s * d) / fmaxf(s * sqrtf(n1 * n2), 1e-8f);
    }
}

extern "C" void kernel_launch(void* const* d_in, const int* in_sizes, int n_in,
                              void* d_out, int out_size, void* d_ws, size_t ws_size,
                              hipStream_t stream)
{
    (void)in_sizes; (void)n_in; (void)out_size; (void)ws_size;
    const float* X  = (const float*)d_in[0];
    const float* W1 = (const float*)d_in[1];
    const float* b1 = (const float*)d_in[2];
    const float* W2 = (const float*)d_in[3];
    const float* b2 = (const float*)d_in[4];
    const float* W3 = (const float*)d_in[5];
    const float* b3 = (const float*)d_in[6];

    float* wsf          = (float*)d_ws;                      // d,n1,n2 : 3x4096 f32
    unsigned short* wsb = (unsigned short*)(wsf + 12288);    // W1 bf16 (98304)
    int* flags          = (int*)((char*)d_ws + 266240);      // wflag + pflag[64]

    hipMemsetAsync(flags, 0, 65 * sizeof(int), stream);      // capture-safe
    fused_pq<<<dim3(576), dim3(512), 0, stream>>>(X, W1, b1, W2, b2, W3, b3,
                                                  wsf, wsb, flags, (float*)d_out);
}